// Round 10
// baseline (58.306 us; speedup 1.0000x reference)
//
#include <hip/hip_runtime.h>

// Problem constants
#define N_  32
#define C_  32
#define H_  56
#define W_  56
#define O_  32
#define HP_ 58   // padded
#define WP_ 58
#define HW_ (H_*W_)          // 3136
#define CHW_ (C_*H_*W_)      // 100352
#define KK_ 9
#define CKK_ (C_*KK_)        // 288
#define WROWB_ 1152          // bytes per weight o-row (288 fp32)
#define WROWSTRIDE_ ((size_t)HW_ * CKK_ * 4)   // bytes between o-rows in global
#define WTILE_B 36864        // one position's weight tile in LDS

// xT layout: [C][HP][WP][N] (zero padded border), bf16
#define XT_ELEMS ((size_t)C_*HP_*WP_*N_)

#define KP_   144   // k-pairs (288/2)
#define PSTR_ 36    // uints per kp-row: 32 n + 4 pad

typedef __bf16 bf16x8 __attribute__((ext_vector_type(8)));
typedef float  f32x4  __attribute__((ext_vector_type(4)));

#define WAIT_VM0()   asm volatile("s_waitcnt vmcnt(0) lgkmcnt(0)" ::: "memory")
#define WAIT_LGKM0() asm volatile("s_waitcnt lgkmcnt(0)" ::: "memory")

__device__ __forceinline__ void gload_lds16(const void* g, void* l) {
    __builtin_amdgcn_global_load_lds(
        (const __attribute__((address_space(1))) unsigned int*)g,
        (__attribute__((address_space(3))) unsigned int*)l,
        16, 0, 0);
}

// -------- transpose + pad + bf16-convert:  x[N][C][H][W] -> xT[C][HP][WP][N] --------
__global__ __launch_bounds__(256) void xpose_kernel(const float* __restrict__ x,
                                                    __bf16* __restrict__ xT) {
    const int c = blockIdx.x;   // 0..31
    const int y = blockIdx.y;   // 0..57 (padded row)
    __shared__ float sb[32 * 57];
    const int tid = threadIdx.x;
    const bool interior = (y >= 1) && (y <= H_);
    if (interior) {
        for (int idx = tid; idx < N_ * W_; idx += 256) {
            int n = idx / W_;
            int col = idx - n * W_;
            sb[n * 57 + col] = x[((size_t)(n * C_ + c) * H_ + (y - 1)) * W_ + col];
        }
    }
    __syncthreads();
    __bf16* dst = xT + ((size_t)(c * HP_ + y)) * WP_ * N_;
    for (int idx = tid; idx < WP_ * N_; idx += 256) {
        int xx = idx >> 5;
        int n  = idx & 31;
        float v = 0.f;
        if (interior && xx >= 1 && xx <= W_) v = sb[n * 57 + (xx - 1)];
        dst[idx] = (__bf16)v;
    }
}

// -------- MFMA main --------
// Block = 4 consecutive w positions at one h; 4 waves = (nh, oh) quadrants.
// T3/T4 pipeline with raw s_barrier + counted vmcnt: W(p+1) is staged via
// global_load_lds (frag-major layout, r9-verified) and stays IN FLIGHT across
// compute(p)+pack(p+1); the only vmcnt(0) drain sits right before W(p+1) is
// consumed — i.e. the drain IS the memory-service pacing point, stream duty
// ~100%. P2 im2col single-buffered: lgkm-only barrier between compute(p) reads
// and pack(p+1) writes keeps the vmcnt queue untouched. Stores go directly
// from acc (scattered 4 B merges in L2 per r8: WRITE_SIZE == out bytes).
__global__ __launch_bounds__(256) void lc2d_mfma(const float* __restrict__ wgt,
                                                 const __bf16* __restrict__ xT,
                                                 const float* __restrict__ bias,
                                                 float* __restrict__ out) {
    __shared__ __align__(16) char wlds[2][WTILE_B];   // 73728 B, frag-major, dbuf
    __shared__ unsigned P2[KP_ * PSTR_];              // 20736 B im2col (single)

    const int tid = threadIdx.x;

    // bijective XCD-chunk swizzle: 784 blocks = 8 XCDs x 98 consecutive wg ids
    const int flat = blockIdx.x;
    const int wg = (flat & 7) * 98 + (flat >> 3);
    const int pt = wg % 14;          // w-tile of 4 (w-major chunks per XCD)
    const int h  = wg / 14;          // 0..55
    const int w0 = pt * 4;
    const int pos0 = h * W_ + w0;

    const int wave = tid >> 6;       // 0..3
    const int lane = tid & 63;
    const int nh = wave & 1;         // n-half quadrant
    const int oh = wave >> 1;        // o-half quadrant
    const int q = lane >> 4;         // k-group 0..3
    const int r = lane & 15;         // o (B-frag) / n (A-frag) within tile

    // ---- weight staging: 9 gload_lds per wave, frag-major dest (r9-verified) ----
    const size_t srcLaneOff = (size_t)r * WROWSTRIDE_ + (size_t)(q * 32);
    const char* wgt_b = (const char*)wgt;
    auto stage_w = [&](int pos, int b) {
        const char* base = wgt_b + (size_t)pos * WROWB_ + srcLaneOff;
        char* dst = wlds[b];
        #pragma unroll
        for (int u = 0; u < 9; ++u) {
            const int t = wave * 9 + u;                 // t = 4s + 2half + oh
            gload_lds16(base + (size_t)(t & 1) * (16 * WROWSTRIDE_)
                             + (unsigned)((t >> 2) * 128 + ((t >> 1) & 1) * 16),
                        dst + t * 1024);
        }
    };

    // ---- x im2col: issue loads to regs, pack to P2 later ----
    uint4 xra[3], xrb[3];
    auto xload = [&](int pidx) {
        const __bf16* xb = xT + (h * WP_ + w0 + pidx) * N_;
        #pragma unroll
        for (int it = 0; it < 3; ++it) {
            const int task = it * 256 + tid;
            if (it < 2 || task < 576) {
                const int kp = task >> 2;
                const int g  = task & 3;
                const int k0 = 2 * kp, k1 = 2 * kp + 1;
                const int c0 = k0 / 9, ij0 = k0 - 9 * c0;
                const int i0 = ij0 / 3, j0 = ij0 - 3 * i0;
                const int c1 = k1 / 9, ij1 = k1 - 9 * c1;
                const int i1 = ij1 / 3, j1 = ij1 - 3 * i1;
                const int off0 = c0 * (HP_ * WP_ * N_) + i0 * (WP_ * N_) + j0 * N_;
                const int off1 = c1 * (HP_ * WP_ * N_) + i1 * (WP_ * N_) + j1 * N_;
                xra[it] = *(const uint4*)(xb + off0 + 8 * g);
                xrb[it] = *(const uint4*)(xb + off1 + 8 * g);
            }
        }
    };
    auto pack_p2 = [&]() {
        #pragma unroll
        for (int it = 0; it < 3; ++it) {
            const int task = it * 256 + tid;
            if (it < 2 || task < 576) {
                const int kp = task >> 2;
                const int g  = task & 3;
                union { uint4 qv; ushort sv[8]; } ua, ub;
                ua.qv = xra[it];
                ub.qv = xrb[it];
                unsigned o0[8];
                #pragma unroll
                for (int m = 0; m < 8; ++m)
                    o0[m] = (unsigned)ua.sv[m] | ((unsigned)ub.sv[m] << 16);
                unsigned* dst = &P2[kp * PSTR_ + 8 * g];
                *(uint4*)(dst)     = make_uint4(o0[0], o0[1], o0[2], o0[3]);
                *(uint4*)(dst + 4) = make_uint4(o0[4], o0[5], o0[6], o0[7]);
            }
        }
    };

    // bias for this thread's 4 positions (o = oh*16 + r), hoisted
    const float4 bq = *(const float4*)(bias + (oh * 16 + r) * HW_ + pos0);
    const float bvp[4] = {bq.x, bq.y, bq.z, bq.w};

    // ---- prologue: x(0), W(0); pack(0); full drain before first compute ----
    xload(0);
    stage_w(pos0, 0);
    pack_p2();                 // compiler-emitted vmcnt waits x only (W newer)
    WAIT_VM0();
    __builtin_amdgcn_s_barrier();
    __builtin_amdgcn_sched_barrier(0);

    #pragma unroll
    for (int p = 0; p < 4; ++p) {
        const int b = p & 1;
        if (p < 3) {
            xload(p + 1);                  // x(p+1) -> regs
            stage_w(pos0 + p + 1, b ^ 1);  // W(p+1) -> other buffer, stays in flight
        }
        // ---- compute position p: quadrant (nh, oh), 9 k-steps ----
        const char* wa = wlds[b] + (oh * 1024 + q * 256 + r * 16);
        const unsigned* pa = &P2[(4 * q) * PSTR_ + nh * 16 + r];
        const float bv = bvp[p];
        f32x4 acc = {bv, bv, bv, bv};
        #pragma unroll
        for (int s = 0; s < 9; ++s) {
            union { unsigned u[4]; bf16x8 v; } a0;
            #pragma unroll
            for (int d = 0; d < 4; ++d)
                a0.u[d] = pa[(16 * s + d) * PSTR_];
            const float4 ba = *(const float4*)(wa + s * 4096);
            const float4 bb = *(const float4*)(wa + s * 4096 + 2048);
            bf16x8 bfB;
            bfB[0] = (__bf16)ba.x; bfB[1] = (__bf16)ba.y; bfB[2] = (__bf16)ba.z; bfB[3] = (__bf16)ba.w;
            bfB[4] = (__bf16)bb.x; bfB[5] = (__bf16)bb.y; bfB[6] = (__bf16)bb.z; bfB[7] = (__bf16)bb.w;
            acc = __builtin_amdgcn_mfma_f32_16x16x32_bf16(a0.v, bfB, acc, 0, 0, 0);
        }
        // ---- store direct from acc (4 B scattered; L2 merges, r8-verified) ----
        const int o = oh * 16 + r;
        const int pos = pos0 + p;
        #pragma unroll
        for (int reg = 0; reg < 4; ++reg) {
            const int n = nh * 16 + q * 4 + reg;
            out[(size_t)n * CHW_ + o * HW_ + pos] = acc[reg];
        }
        if (p < 3) {
            // retire all waves' P2/W reads WITHOUT touching vmcnt (W(p+1) flying)
            WAIT_LGKM0();
            __builtin_amdgcn_s_barrier();
            pack_p2();                     // waits x(p+1) regs only (compiler vmcnt)
            // pacing drain: W(p+1) must be in LDS before next compute
            WAIT_VM0();
            __builtin_amdgcn_s_barrier();
            __builtin_amdgcn_sched_barrier(0);
        }
    }
}

// -------- fallback (if workspace too small): thread per output, bounds-checked --------
__global__ __launch_bounds__(256) void lc2d_naive(const float* __restrict__ x,
                                                  const float* __restrict__ wgt,
                                                  const float* __restrict__ bias,
                                                  float* __restrict__ out) {
    int idx = blockIdx.x * 256 + threadIdx.x;
    const int total = N_ * O_ * H_ * W_;
    if (idx >= total) return;
    int w = idx % W_;
    int h = (idx / W_) % H_;
    int o = (idx / HW_) % O_;
    int n = idx / CHW_;
    const float* wp = wgt + ((size_t)((o * H_ + h) * W_ + w)) * CKK_;
    float s = 0.f;
    for (int c = 0; c < C_; ++c) {
        for (int i = 0; i < 3; ++i) {
            int yy = h + i - 1;
            if (yy < 0 || yy >= H_) continue;
            for (int j = 0; j < 3; ++j) {
                int xx = w + j - 1;
                if (xx < 0 || xx >= W_) continue;
                s = fmaf(wp[c * KK_ + i * 3 + j],
                         x[((size_t)(n * C_ + c) * H_ + yy) * W_ + xx], s);
            }
        }
    }
    out[idx] = s + bias[idx % CHW_];
}

extern "C" void kernel_launch(void* const* d_in, const int* in_sizes, int n_in,
                              void* d_out, int out_size, void* d_ws, size_t ws_size,
                              hipStream_t stream) {
    const float* x    = (const float*)d_in[0];
    const float* wgt  = (const float*)d_in[1];
    const float* bias = (const float*)d_in[2];
    float* out = (float*)d_out;

    const size_t need = XT_ELEMS * sizeof(__bf16);
    if (ws_size >= need) {
        __bf16* xT = (__bf16*)d_ws;
        hipLaunchKernelGGL(xpose_kernel, dim3(C_, HP_), dim3(256), 0, stream, x, xT);
        hipLaunchKernelGGL(lc2d_mfma, dim3(784), dim3(256), 0, stream, wgt, xT, bias, out);
    } else {
        int total = N_ * O_ * H_ * W_;
        hipLaunchKernelGGL(lc2d_naive, dim3((total + 255) / 256), dim3(256), 0, stream,
                           x, wgt, bias, out);
    }
}

// Round 11
// 49.908 us; speedup vs baseline: 1.1683x; 1.1683x over previous
//
#include <hip/hip_runtime.h>

// Problem constants
#define N_  32
#define C_  32
#define H_  56
#define W_  56
#define O_  32
#define HP_ 58   // padded
#define WP_ 58
#define HW_ (H_*W_)          // 3136
#define CHW_ (C_*H_*W_)      // 100352
#define KK_ 9
#define CKK_ (C_*KK_)        // 288

// xT layout: [C][HP][WP][N] (zero padded border), bf16
#define XT_ELEMS ((size_t)C_*HP_*WP_*N_)

#define KP_   144   // k-pairs (288/2)
#define PSTR_ 36    // uints per kp-row: 32 n + 4 pad

typedef __bf16 bf16x8 __attribute__((ext_vector_type(8)));
typedef float  f32x4  __attribute__((ext_vector_type(4)));

#define WAIT_LGKM0() asm volatile("s_waitcnt lgkmcnt(0)" ::: "memory")
#define RAW_BAR()    asm volatile("s_barrier" ::: "memory")

// -------- transpose + pad + bf16-convert:  x[N][C][H][W] -> xT[C][HP][WP][N] --------
__global__ __launch_bounds__(256) void xpose_kernel(const float* __restrict__ x,
                                                    __bf16* __restrict__ xT) {
    const int c = blockIdx.x;   // 0..31
    const int y = blockIdx.y;   // 0..57 (padded row)
    __shared__ float sb[32 * 57];
    const int tid = threadIdx.x;
    const bool interior = (y >= 1) && (y <= H_);
    if (interior) {
        for (int idx = tid; idx < N_ * W_; idx += 256) {
            int n = idx / W_;
            int col = idx - n * W_;
            sb[n * 57 + col] = x[((size_t)(n * C_ + c) * H_ + (y - 1)) * W_ + col];
        }
    }
    __syncthreads();
    __bf16* dst = xT + ((size_t)(c * HP_ + y)) * WP_ * N_;
    for (int idx = tid; idx < WP_ * N_; idx += 256) {
        int xx = idx >> 5;
        int n  = idx & 31;
        float v = 0.f;
        if (interior && xx >= 1 && xx <= W_) v = sb[n * 57 + (xx - 1)];
        dst[idx] = (__bf16)v;
    }
}

// -------- MFMA main --------
// Block = 1x4 w-strip at one h; 4 waves = (dw, oh); 2 w-pairs processed
// sequentially (r6's proven P2-im2col inner loop per pair).
// x read ONCE per strip into win[32c][3y][6xx][32n] (fully coalesced from
// padded xT, zero branches) -> P2 built from LDS (x L1-ingress halved vs r6).
// All 36 weight float4 (both pairs) issued before the first barrier; raw
// s_barrier + lgkm-only waits never drain vmcnt, so the 115.6 MB read-once
// weight stream flows continuously across build/compute phases.
__global__ __launch_bounds__(256, 2) void lc2d_mfma(const float* __restrict__ wgt,
                                                    const __bf16* __restrict__ xT,
                                                    const float* __restrict__ bias,
                                                    float* __restrict__ out) {
    __shared__ __align__(16) char win[36864];         // [c][3y][6xx][32n] bf16
    __shared__ unsigned P2[2 * KP_ * PSTR_];          // 41472 B (2 positions)

    const int tid = threadIdx.x;

    // bijective XCD-chunk swizzle: 784 blocks = 8 XCDs x 98 consecutive wg ids
    const int flat = blockIdx.x;
    const int wg = (flat & 7) * 98 + (flat >> 3);
    const int wt = wg % 14;          // w-strip of 4 (w-major chunks per XCD)
    const int h  = wg / 14;          // 0..55
    const int w0 = wt * 4;

    const int wave = tid >> 6;       // 0..3
    const int lane = tid & 63;
    const int dw = wave & 1;         // position within pair
    const int oh = wave >> 1;        // o-half
    const int q = lane >> 4;         // k-group 0..3
    const int r = lane & 15;         // o (B-frag) / n (A-frag) within tile

    // ---- section 1: window global loads (9 x uint4, fully coalesced) ----
    // task = (c*3+y)*24 + xx*4 + g ; src xT[c][h+y][w0+xx][8g..8g+7]
    uint4 wreg[9];
    #pragma unroll
    for (int u = 0; u < 9; ++u) {
        const int task = u * 256 + tid;
        const int cy = task / 24;
        const int ch = task - cy * 24;
        const int c  = cy / 3;
        const int y  = cy - 3 * c;
        const int xx = ch >> 2;
        const int g  = ch & 3;
        wreg[u] = *(const uint4*)(xT + ((size_t)(c * HP_ + h + y) * WP_ + (w0 + xx)) * N_ + 8 * g);
    }
    // ---- section 2: window -> LDS (linear; compiler waits win vmcnt only) ----
    #pragma unroll
    for (int u = 0; u < 9; ++u)
        *(uint4*)(win + (u * 256 + tid) * 16) = wreg[u];

    // ---- section 3: ALL weight loads (both pairs) + bias, before barrier ----
    const char* wbB = (const char*)wgt
        + (size_t)((oh * 16 + r) * HW_ + h * W_ + (w0 + dw)) * 1152 + q * 32;
    float4 wv0[18], wv1[18];
    #pragma unroll
    for (int s = 0; s < 9; ++s) {
        wv0[2 * s]     = *(const float4*)(wbB + s * 128);
        wv0[2 * s + 1] = *(const float4*)(wbB + s * 128 + 16);
        wv1[2 * s]     = *(const float4*)(wbB + s * 128 + 2304);
        wv1[2 * s + 1] = *(const float4*)(wbB + s * 128 + 2304 + 16);
    }
    const float bv0 = bias[(oh * 16 + r) * HW_ + h * W_ + (w0 + dw)];
    const float bv1 = bias[(oh * 16 + r) * HW_ + h * W_ + (w0 + 2 + dw)];
    __builtin_amdgcn_sched_barrier(0);

    WAIT_LGKM0();
    RAW_BAR();          // window visible to all waves; weight stream stays in flight

    // ---- per-pair: build P2 from win, then r6 MFMA loop ----
    const unsigned* pa = &P2[(dw * KP_ + 4 * q) * PSTR_ + r];
    f32x4 accs[4];

    #pragma unroll
    for (int dwp = 0; dwp < 2; ++dwp) {
        // build P2 for positions (w0+dwp*2+0, +1): 1152 tasks from win LDS
        #pragma unroll
        for (int it = 0; it < 5; ++it) {
            const int task = it * 256 + tid;
            if (it < 4 || task < 1152) {
                const int tdw = task / 576;
                const int rem = task - tdw * 576;
                const int kp  = rem >> 2;
                const int g   = rem & 3;
                const int k0 = 2 * kp, k1 = 2 * kp + 1;
                const int c0 = k0 / 9, ij0 = k0 - 9 * c0;
                const int i0 = ij0 / 3, j0 = ij0 - 3 * i0;
                const int c1 = k1 / 9, ij1 = k1 - 9 * c1;
                const int i1 = ij1 / 3, j1 = ij1 - 3 * i1;
                const int col0 = dwp * 2 + tdw + j0;
                const int col1 = dwp * 2 + tdw + j1;
                union { uint4 qv; ushort sv[8]; } ua, ub;
                ua.qv = *(const uint4*)(win + (c0 * 18 + i0 * 6 + col0) * 64 + g * 16);
                ub.qv = *(const uint4*)(win + (c1 * 18 + i1 * 6 + col1) * 64 + g * 16);
                unsigned o0[8];
                #pragma unroll
                for (int m = 0; m < 8; ++m)
                    o0[m] = (unsigned)ua.sv[m] | ((unsigned)ub.sv[m] << 16);
                unsigned* dst = &P2[(tdw * KP_ + kp) * PSTR_ + 8 * g];
                *(uint4*)(dst)     = make_uint4(o0[0], o0[1], o0[2], o0[3]);
                *(uint4*)(dst + 4) = make_uint4(o0[4], o0[5], o0[6], o0[7]);
            }
        }
        WAIT_LGKM0();
        RAW_BAR();      // P2(dwp) ready

        f32x4 acc0 = {0.f, 0.f, 0.f, 0.f};   // n 0..15
        f32x4 acc1 = {0.f, 0.f, 0.f, 0.f};   // n 16..31
        #pragma unroll
        for (int s = 0; s < 9; ++s) {
            union { unsigned u[4]; bf16x8 v; } a0, a1;
            #pragma unroll
            for (int d = 0; d < 4; ++d) {
                a0.u[d] = pa[(16 * s + d) * PSTR_];
                a1.u[d] = pa[(16 * s + d) * PSTR_ + 16];
            }
            const float4 ba = dwp == 0 ? wv0[2 * s]     : wv1[2 * s];
            const float4 bb = dwp == 0 ? wv0[2 * s + 1] : wv1[2 * s + 1];
            bf16x8 bfB;
            bfB[0] = (__bf16)ba.x; bfB[1] = (__bf16)ba.y; bfB[2] = (__bf16)ba.z; bfB[3] = (__bf16)ba.w;
            bfB[4] = (__bf16)bb.x; bfB[5] = (__bf16)bb.y; bfB[6] = (__bf16)bb.z; bfB[7] = (__bf16)bb.w;
            acc0 = __builtin_amdgcn_mfma_f32_16x16x32_bf16(a0.v, bfB, acc0, 0, 0, 0);
            acc1 = __builtin_amdgcn_mfma_f32_16x16x32_bf16(a1.v, bfB, acc1, 0, 0, 0);
        }
        accs[2 * dwp]     = acc0;
        accs[2 * dwp + 1] = acc1;
        if (dwp == 0) { RAW_BAR(); }   // all waves done reading P2(0) before rebuild
    }

    // ---- stores: direct from acc (scattered 4 B; L2 merges, r8-verified) ----
    #pragma unroll
    for (int dwp = 0; dwp < 2; ++dwp) {
        const int pos = h * W_ + w0 + dwp * 2 + dw;
        const float bv = dwp == 0 ? bv0 : bv1;
        const int o = oh * 16 + r;
        #pragma unroll
        for (int reg = 0; reg < 4; ++reg) {
            const int m = q * 4 + reg;
            out[(size_t)m * CHW_ + o * HW_ + pos]        = accs[2 * dwp][reg] + bv;
            out[(size_t)(m + 16) * CHW_ + o * HW_ + pos] = accs[2 * dwp + 1][reg] + bv;
        }
    }
}

// -------- fallback (if workspace too small): thread per output, bounds-checked --------
__global__ __launch_bounds__(256) void lc2d_naive(const float* __restrict__ x,
                                                  const float* __restrict__ wgt,
                                                  const float* __restrict__ bias,
                                                  float* __restrict__ out) {
    int idx = blockIdx.x * 256 + threadIdx.x;
    const int total = N_ * O_ * H_ * W_;
    if (idx >= total) return;
    int w = idx % W_;
    int h = (idx / W_) % H_;
    int o = (idx / HW_) % O_;
    int n = idx / CHW_;
    const float* wp = wgt + ((size_t)((o * H_ + h) * W_ + w)) * CKK_;
    float s = 0.f;
    for (int c = 0; c < C_; ++c) {
        for (int i = 0; i < 3; ++i) {
            int yy = h + i - 1;
            if (yy < 0 || yy >= H_) continue;
            for (int j = 0; j < 3; ++j) {
                int xx = w + j - 1;
                if (xx < 0 || xx >= W_) continue;
                s = fmaf(wp[c * KK_ + i * 3 + j],
                         x[((size_t)(n * C_ + c) * H_ + yy) * W_ + xx], s);
            }
        }
    }
    out[idx] = s + bias[idx % CHW_];
}

extern "C" void kernel_launch(void* const* d_in, const int* in_sizes, int n_in,
                              void* d_out, int out_size, void* d_ws, size_t ws_size,
                              hipStream_t stream) {
    const float* x    = (const float*)d_in[0];
    const float* wgt  = (const float*)d_in[1];
    const float* bias = (const float*)d_in[2];
    float* out = (float*)d_out;

    const size_t need = XT_ELEMS * sizeof(__bf16);
    if (ws_size >= need) {
        __bf16* xT = (__bf16*)d_ws;
        hipLaunchKernelGGL(xpose_kernel, dim3(C_, HP_), dim3(256), 0, stream, x, xT);
        hipLaunchKernelGGL(lc2d_mfma, dim3(784), dim3(256), 0, stream, wgt, xT, bias, out);
    } else {
        int total = N_ * O_ * H_ * W_;
        hipLaunchKernelGGL(lc2d_naive, dim3((total + 255) / 256), dim3(256), 0, stream,
                           x, wgt, bias, out);
    }
}